// Round 1
// 420.312 us; speedup vs baseline: 1.0598x; 1.0598x over previous
//
#include <hip/hip_runtime.h>
#include <math.h>

#define VOCAB 32768
#define DD 512
#define NB 3
#define NF 3
#define SEQ 4
#define MAX_ENT_F 10.3972077083991790f

// scratch layout inside o_rho[t] (262144 floats, dead until k_rho_tok):
#define SCR_ST   0        // [9][8][512] states partials = 36864
#define SCR_PART 36864    // [12][2048] born-moment partials = 24576
#define SCR_G    61440    // [45] Gram
#define SCR_BORN 65536    // [3][VOCAB] = 98304

// pair index tables for i<=j over 9 (45 pairs)
__device__ const unsigned char PI9[45] = {
  0,0,0,0,0,0,0,0,0, 1,1,1,1,1,1,1,1, 2,2,2,2,2,2,2, 3,3,3,3,3,3,
  4,4,4,4,4, 5,5,5,5, 6,6,6, 7,7, 8};
__device__ const unsigned char PJ9[45] = {
  0,1,2,3,4,5,6,7,8, 1,2,3,4,5,6,7,8, 2,3,4,5,6,7,8, 3,4,5,6,7,8,
  4,5,6,7,8, 5,6,7,8, 6,7,8, 7,8, 8};

// ---- round-robin Jacobi schedule for n=9 (9 rounds x 4 disjoint pairs; all 36 pairs once) ----
// round r pivot pairs (p_k, q_k), k=0..3:
__device__ const unsigned char RP9[9][4] = {
  {1,2,3,4},{0,1,2,3},{0,6,1,2},{0,5,4,1},{0,4,3,2},{0,3,2,1},{0,2,1,7},{0,1,5,6},{0,3,4,5}};
__device__ const unsigned char RQ9[9][4] = {
  {8,7,6,5},{8,6,5,4},{7,8,4,3},{6,7,8,2},{5,6,7,8},{4,5,6,7},{3,4,5,8},{2,3,8,7},{1,8,7,6}};
// per-round, per-index: pair id (4 = bye/identity), sign of s in u_i, partner index
__device__ const unsigned char K9R[9][9] = {
  {4,0,1,2,3,3,2,1,0},
  {0,1,2,3,3,2,1,4,0},
  {0,2,3,3,2,4,1,0,1},
  {0,3,3,4,2,1,0,1,2},
  {0,4,3,2,1,0,1,2,3},
  {0,3,2,1,0,1,2,3,4},
  {0,2,1,0,1,2,4,3,3},
  {0,1,0,1,4,2,3,3,2},
  {0,0,4,1,2,3,3,2,1}};
__device__ const signed char SG9R[9][9] = {
  { 1,-1,-1,-1,-1, 1, 1, 1, 1},
  {-1,-1,-1,-1, 1, 1, 1, 1, 1},
  {-1,-1,-1, 1, 1, 1,-1, 1, 1},
  {-1,-1, 1, 1,-1,-1, 1, 1, 1},
  {-1, 1,-1,-1,-1, 1, 1, 1, 1},
  {-1,-1,-1,-1, 1, 1, 1, 1, 1},
  {-1,-1,-1, 1, 1, 1, 1,-1, 1},
  {-1,-1, 1, 1, 1,-1,-1, 1, 1},
  {-1, 1, 1,-1,-1,-1, 1, 1, 1}};
__device__ const unsigned char PT9R[9][9] = {
  {0,8,7,6,5,4,3,2,1},
  {8,6,5,4,3,2,1,7,0},
  {7,4,3,2,1,5,8,0,6},
  {6,2,1,3,8,7,0,5,4},
  {5,1,8,7,6,0,4,3,2},
  {4,7,6,5,0,3,2,1,8},
  {3,5,4,0,2,1,6,8,7},
  {2,3,0,1,4,8,7,6,5},
  {1,0,2,8,7,6,5,4,3}};

__device__ __forceinline__ float blockReduceSum(float v, float* sh) {
  int lane = threadIdx.x & 63;
  int wid  = threadIdx.x >> 6;
#pragma unroll
  for (int off = 32; off; off >>= 1) v += __shfl_down(v, off, 64);
  __syncthreads();
  if (lane == 0) sh[wid] = v;
  __syncthreads();
  int nw = blockDim.x >> 6;
  float r = 0.0f;
  if ((int)threadIdx.x < nw) r = sh[threadIdx.x];
  if (wid == 0) {
#pragma unroll
    for (int off = 8; off; off >>= 1) r += __shfl_down(r, off, 64);
    if (lane == 0) sh[0] = r;
  }
  __syncthreads();
  return sh[0];
}

__global__ void k_zero(float* p, int n) {
  int i = blockIdx.x * blockDim.x + threadIdx.x;
  if (i < n) p[i] = 0.0f;
}

// pre (redundant per block) + states K-chunk GEMV partials.
// grid (9, 8): fn = f*3+n, dc = K-chunk. 256 threads.
__global__ void k_states(const int* __restrict__ tokens, const float* __restrict__ E,
                         const float* __restrict__ mem, const float* __restrict__ Ws,
                         const float* __restrict__ base_p, const float* __restrict__ sens_p,
                         float* __restrict__ decayArr, float* __restrict__ scr_st, int t) {
  const int fn = blockIdx.x, dc = blockIdx.y, tid = threadIdx.x;
  const int f = fn / NB;
  const int d0 = dc * 64;
  __shared__ float smean[DD];
  __shared__ float xin_loc[64];
  __shared__ float red[16];
  __shared__ float s_decay;
  const float* x = E + (size_t)tokens[t] * DD;
  const float* m = mem + f * (NB * DD);
  for (int d = tid; d < DD; d += 256)
    smean[d] = (m[d] + m[DD + d] + m[2 * DD + d]) * (1.0f / 3.0f);
  __syncthreads();
  float pxm = 0.f, pxx = 0.f, pmm = 0.f;
  for (int d = tid; d < DD; d += 256) {
    float xv = x[d], mv = smean[d];
    pxm += xv * mv; pxx += xv * xv; pmm += mv * mv;
  }
  float sxm = blockReduceSum(pxm, red);
  float sxx = blockReduceSum(pxx, red);
  float smm = blockReduceSum(pmm, red);
  if (tid == 0) {
    float mem_norm = sqrtf(smm) + 1e-10f;
    float x_norm   = sqrtf(sxx) + 1e-10f;
    float novelty  = (mem_norm > 1e-8f) ? (1.0f - sxm / (x_norm * mem_norm)) : 1.0f;
    float sens = fabsf(sens_p[0]);
    float z = base_p[0] - sens * novelty;
    float dec = 1.0f / (1.0f + expf(-z));
    if (dc == 0 && fn % NB == 0) decayArr[f] = dec;
    s_decay = dec;
  }
  __syncthreads();
  if (tid < 64) xin_loc[tid] = x[d0 + tid] + s_decay * smean[d0 + tid];
  __syncthreads();
  const float* W = Ws + (size_t)fn * DD * DD + (size_t)d0 * DD;
  float acc0 = 0.f, acc1 = 0.f;
#pragma unroll 8
  for (int dd = 0; dd < 64; dd++) {
    float xv = xin_loc[dd];
    acc0 += xv * W[dd * DD + tid];
    acc1 += xv * W[dd * DD + tid + 256];
  }
  float* o = scr_st + (fn * 8 + dc) * DD;
  o[tid] = acc0;
  o[tid + 256] = acc1;
}

// sum K-chunks, equilibrate, norms, bubble weights, normed, memory update
__global__ void k_equil(const float* __restrict__ scr_st, float* __restrict__ mem,
                        float* __restrict__ normed, float* __restrict__ wbub,
                        const float* __restrict__ decayArr) {
  const int f = blockIdx.x, tid = threadIdx.x;   // 256 threads
  __shared__ float s[NB * DD];
  __shared__ float red[16];
  __shared__ float snrm[NB];
  for (int i = tid; i < NB * DD; i += 256) {
    int n = i >> 9, e = i & 511;
    const float* src = scr_st + ((f * NB + n) * 8) * DD + e;
    float acc = 0.f;
#pragma unroll
    for (int dc = 0; dc < 8; dc++) acc += src[dc * DD];
    s[i] = acc;
  }
  __syncthreads();
  for (int e = tid; e < DD; e += 256) {
    float a = s[e], b = s[DD + e], c = s[2 * DD + e];
#pragma unroll
    for (int it = 0; it < 3; it++) {
      float mn = (a + b + c) * (1.0f / 3.0f);
      a += 0.3f * (mn - a);
      b += 0.3f * (mn - b);
      c += 0.3f * (mn - c);
    }
    s[e] = a; s[DD + e] = b; s[2 * DD + e] = c;
  }
  __syncthreads();
  for (int n = 0; n < NB; n++) {
    float p = 0.f;
    for (int e = tid; e < DD; e += 256) { float v = s[n * DD + e]; p += v * v; }
    float ss = blockReduceSum(p, red);
    if (tid == 0) snrm[n] = sqrtf(ss);
  }
  __syncthreads();
  if (tid == 0) {
    float n0 = snrm[0], n1 = snrm[1], n2 = snrm[2];
    float mx = fmaxf(2.0f * n0, fmaxf(2.0f * n1, 2.0f * n2));
    float e0 = expf(2.0f * n0 - mx), e1 = expf(2.0f * n1 - mx), e2 = expf(2.0f * n2 - mx);
    float sd = e0 + e1 + e2;
    wbub[f * NB + 0] = e0 / sd;
    wbub[f * NB + 1] = e1 / sd;
    wbub[f * NB + 2] = e2 / sd;
  }
  float dec = decayArr[f];
  for (int i = tid; i < NB * DD; i += 256) {
    int n = i >> 9;
    float sv = s[i];
    normed[f * NB * DD + i] = sv / (snrm[n] + 1e-10f);
    float old = mem[f * NB * DD + i];
    mem[f * NB * DD + i] = dec * old + (1.0f - dec) * sv;
  }
}

// born -> scr_born; 12 moment-partials of u=exp(born) per block; Gram in block 0.
__global__ __launch_bounds__(256) void k_born(const float4* __restrict__ E4,
                                              const float4* __restrict__ N4,
                                              const float* __restrict__ wbub,
                                              float* __restrict__ scr) {
  const int tid = threadIdx.x, lane = tid & 63, wave = tid >> 6;
  float* born = scr + SCR_BORN;
  float4 nr0[9], nr1[9];
#pragma unroll
  for (int j = 0; j < 9; j++) {
    nr0[j] = N4[j * 128 + lane];
    nr1[j] = N4[j * 128 + 64 + lane];
  }
  __shared__ float w9[9];
  __shared__ float sb2[12][4];
  if (tid < 9) w9[tid] = wbub[tid];
  __syncthreads();
  float pu0 = 0.f, pu1 = 0.f, pu2 = 0.f;
  float pub0 = 0.f, pub1 = 0.f, pub2 = 0.f;
  float puu0 = 0.f, puu1 = 0.f, puu2 = 0.f;
  float pc01 = 0.f, pc02 = 0.f, pc12 = 0.f;
  const int vbase = blockIdx.x * 16 + wave * 4;
#pragma unroll
  for (int r = 0; r < 4; r++) {
    int v = vbase + r;
    float4 a0 = E4[v * 128 + lane];
    float4 a1 = E4[v * 128 + 64 + lane];
    float acc[9];
#pragma unroll
    for (int j = 0; j < 9; j++) {
      float4 p = nr0[j], q = nr1[j];
      acc[j] = a0.x * p.x + a0.y * p.y + a0.z * p.z + a0.w * p.w +
               a1.x * q.x + a1.y * q.y + a1.z * q.z + a1.w * q.w;
    }
#pragma unroll
    for (int j = 0; j < 9; j++) {
      float a = acc[j];
#pragma unroll
      for (int off = 32; off; off >>= 1) a += __shfl_down(a, off, 64);
      acc[j] = a;
    }
    if (lane == 0) {
      float b0 = w9[0] * acc[0] * acc[0] + w9[1] * acc[1] * acc[1] + w9[2] * acc[2] * acc[2];
      float b1 = w9[3] * acc[3] * acc[3] + w9[4] * acc[4] * acc[4] + w9[5] * acc[5] * acc[5];
      float b2 = w9[6] * acc[6] * acc[6] + w9[7] * acc[7] * acc[7] + w9[8] * acc[8] * acc[8];
      born[v] = b0; born[VOCAB + v] = b1; born[2 * VOCAB + v] = b2;
      float u0 = expf(b0), u1 = expf(b1), u2 = expf(b2);
      pu0 += u0; pu1 += u1; pu2 += u2;
      pub0 += u0 * b0; pub1 += u1 * b1; pub2 += u2 * b2;
      puu0 += u0 * u0; puu1 += u1 * u1; puu2 += u2 * u2;
      pc01 += u0 * u1; pc02 += u0 * u2; pc12 += u1 * u2;
    }
  }
  if (lane == 0) {
    sb2[0][wave] = pu0;  sb2[1][wave] = pu1;  sb2[2][wave] = pu2;
    sb2[3][wave] = pub0; sb2[4][wave] = pub1; sb2[5][wave] = pub2;
    sb2[6][wave] = puu0; sb2[7][wave] = puu1; sb2[8][wave] = puu2;
    sb2[9][wave] = pc01; sb2[10][wave] = pc02; sb2[11][wave] = pc12;
  }
  __syncthreads();
  if (tid < 12) {
    float s = sb2[tid][0] + sb2[tid][1] + sb2[tid][2] + sb2[tid][3];
    scr[SCR_PART + tid * 2048 + blockIdx.x] = s;
  }
  // Gram (block 0 only): 45 pairs x 4 lanes
  if (blockIdx.x == 0 && tid < 180) {
    const int p = tid >> 2, sub = tid & 3;
    const float4* ni = N4 + (int)PI9[p] * 128;
    const float4* nj = N4 + (int)PJ9[p] * 128;
    float s = 0.f;
#pragma unroll
    for (int it = 0; it < 32; it++) {
      float4 a = ni[sub * 32 + it];
      float4 b = nj[sub * 32 + it];
      s += a.x * b.x + a.y * b.y + a.z * b.z + a.w * b.w;
    }
    s += __shfl_down(s, 2, 4);
    s += __shfl_down(s, 1, 4);
    if (sub == 0) scr[SCR_G + p] = s;
  }
}

// Reduce 12x2048 partials (4 waves), scalar head on lane 0, then a LANE-PARALLEL
// round-robin Jacobi: 9 rounds x 4 disjoint pivot pairs per sweep. Lanes 0-3
// compute the 4 rotation angles concurrently (the only serial chain left);
// lanes 0-44 each rebuild one upper-triangle element of A' = J^T A J from the
// old matrix (u_i^T A u_j, <=2 nonzeros per u => 4 LDS reads + 8 flops) into a
// ping-pong LDS buffer. Replaces ~86us of single-lane serial dependent-chain
// Jacobi with ~45 parallel rounds. 6 sweeps (1 more than the serial version)
// absorb the ordering change + non-exact pivot zeroing.
__global__ __launch_bounds__(256, 1) void k_scal(const float* __restrict__ scr,
                                                 const float* __restrict__ wbub,
                                                 const float* __restrict__ temp_p,
                                                 float* __restrict__ o_w, float* __restrict__ o_sr,
                                                 float* __restrict__ wmeta, float* __restrict__ logSf,
                                                 float* __restrict__ coeff, float* __restrict__ srho_ws) {
  const int tid = threadIdx.x, lane = tid & 63, wave = tid >> 6;
  __shared__ float r12[12];
  __shared__ float A2f[162];     // ping-pong 9x9
  __shared__ float csC[5], csS[5];  // slot 4 = identity (bye)
  __shared__ float sq9s[9];
#pragma unroll
  for (int jj = 0; jj < 3; jj++) {
    const int j = wave * 3 + jj;
    const float* src = scr + SCR_PART + j * 2048;
    float s = 0.f;
#pragma unroll
    for (int b = 0; b < 32; b++) s += src[lane + b * 64];
#pragma unroll
    for (int off = 32; off; off >>= 1) s += __shfl_down(s, off, 64);
    if (lane == 0) r12[j] = s;
  }
  __syncthreads();
  if (tid == 0) {
    float S0 = r12[0], S1 = r12[1], S2 = r12[2];
    float lg0 = logf(S0), lg1 = logf(S1), lg2 = logf(S2);
    logSf[0] = lg0; logSf[1] = lg1; logSf[2] = lg2;
    float H0 = lg0 - r12[3] / S0;
    float H1 = lg1 - r12[4] / S1;
    float H2 = lg2 - r12[5] / S2;
    float c0 = 1.0f - H0 / MAX_ENT_F;
    float c1 = 1.0f - H1 / MAX_ENT_F;
    float c2 = 1.0f - H2 / MAX_ENT_F;
    float np0 = sqrtf(r12[6]) / S0 + 1e-10f;
    float np1 = sqrtf(r12[7]) / S1 + 1e-10f;
    float np2 = sqrtf(r12[8]) / S2 + 1e-10f;
    float A01 = (r12[9]  / (S0 * S1)) / (np0 * np1);
    float A02 = (r12[10] / (S0 * S2)) / (np0 * np2);
    float A12 = (r12[11] / (S1 * S2)) / (np1 * np2);
    float ag0 = 0.5f * (A01 + A02);
    float ag1 = 0.5f * (A01 + A12);
    float ag2 = 0.5f * (A02 + A12);
    float temp = fmaxf(fabsf(temp_p[0]), 0.01f);
    float z0 = c0 * ag0 / temp, z1 = c1 * ag1 / temp, z2 = c2 * ag2 / temp;
    float mz = fmaxf(z0, fmaxf(z1, z2));
    float e0 = expf(z0 - mz), e1 = expf(z1 - mz), e2 = expf(z2 - mz);
    float sd = e0 + e1 + e2;
    float wm0 = e0 / sd, wm1 = e1 / sd, wm2 = e2 / sd;
    o_w[0] = wm0; o_w[1] = wm1; o_w[2] = wm2;
    wmeta[0] = wm0; wmeta[1] = wm1; wmeta[2] = wm2;
    float cf0 = wm0 * wbub[0], cf1 = wm0 * wbub[1], cf2 = wm0 * wbub[2];
    float cf3 = wm1 * wbub[3], cf4 = wm1 * wbub[4], cf5 = wm1 * wbub[5];
    float cf6 = wm2 * wbub[6], cf7 = wm2 * wbub[7], cf8 = wm2 * wbub[8];
    coeff[0] = cf0; coeff[1] = cf1; coeff[2] = cf2;
    coeff[3] = cf3; coeff[4] = cf4; coeff[5] = cf5;
    coeff[6] = cf6; coeff[7] = cf7; coeff[8] = cf8;
    sq9s[0] = sqrtf(cf0); sq9s[1] = sqrtf(cf1); sq9s[2] = sqrtf(cf2);
    sq9s[3] = sqrtf(cf3); sq9s[4] = sqrtf(cf4); sq9s[5] = sqrtf(cf5);
    sq9s[6] = sqrtf(cf6); sq9s[7] = sqrtf(cf7); sq9s[8] = sqrtf(cf8);
    csC[4] = 1.0f; csS[4] = 0.0f;
  }
  __syncthreads();
  // init M = diag(sq) G diag(sq), full symmetric 9x9 into buffer 0
  if (tid < 45) {
    const int i = PI9[tid], j = PJ9[tid];
    float v = sq9s[i] * sq9s[j] * scr[SCR_G + tid];
    A2f[i * 9 + j] = v;
    A2f[j * 9 + i] = v;
  }
  __syncthreads();
  int li = 0, lj = 0;
  if (tid < 45) { li = PI9[tid]; lj = PJ9[tid]; }
#pragma unroll 1
  for (int sweep = 0; sweep < 6; sweep++) {
    const int sp = (sweep & 1) * 81;
#pragma unroll
    for (int r = 0; r < 9; r++) {
      const int cur = sp ^ ((r & 1) * 81);   // parity of (sweep*9 + r)
      const int nxt = cur ^ 81;
      if (tid < 4) {
        const int p = RP9[r][tid], q = RQ9[r][tid];
        float app = A2f[cur + p * 9 + p];
        float apq = A2f[cur + p * 9 + q];
        float aqq = A2f[cur + q * 9 + q];
        float den = (fabsf(apq) > 1e-25f) ? apq : 1e-25f;
        float th  = 0.5f * (aqq - app) * __builtin_amdgcn_rcpf(den);
        float mag = __builtin_amdgcn_rcpf(fabsf(th) +
                      __builtin_amdgcn_sqrtf(th * th + 1.f));
        float tt  = copysignf(mag, th);
        float cc  = __builtin_amdgcn_rsqf(tt * tt + 1.f);
        csC[tid] = cc;
        csS[tid] = tt * cc;
      }
      __syncthreads();
      if (tid < 45) {
        const int ki = K9R[r][li], kj = K9R[r][lj];
        const int ip = PT9R[r][li], jp = PT9R[r][lj];
        float ci = csC[ki], si = csS[ki];
        float cj = csC[kj], sj = csS[kj];
        si = (SG9R[r][li] < 0) ? -si : si;
        sj = (SG9R[r][lj] < 0) ? -sj : sj;
        float v = ci * cj * A2f[cur + li * 9 + lj]
                + ci * sj * A2f[cur + li * 9 + jp]
                + si * cj * A2f[cur + ip * 9 + lj]
                + si * sj * A2f[cur + ip * 9 + jp];
        A2f[nxt + li * 9 + lj] = v;
        A2f[nxt + lj * 9 + li] = v;
      }
      __syncthreads();
    }
  }
  // 54 rounds -> final matrix parity is buffer 0
  if (tid == 0) {
    float total = 503.0f * 1e-12f;
    float ev[9];
#pragma unroll
    for (int i = 0; i < 9; i++) { ev[i] = fmaxf(A2f[i * 9 + i], 1e-12f); total += ev[i]; }
    float S = 0.f;
#pragma unroll
    for (int i = 0; i < 9; i++) {
      float q = ev[i] / total;
      S -= q * fmaxf(logf(q), -100.0f);
    }
    float q0 = 1e-12f / total;
    S -= 503.0f * (q0 * fmaxf(logf(q0), -100.0f));
    o_sr[0] = S; srho_ws[0] = S;
  }
}

// write per-foam probs p=exp(b-logS_f) to o_d; token-softmax partials (shift=0)
__global__ void k_t1(const float* __restrict__ scr, const float* __restrict__ logSf,
                     const float* __restrict__ wmeta, float* __restrict__ o_d,
                     float* __restrict__ wt) {
  const int tid = threadIdx.x;   // 128 blocks x 256
  __shared__ float sc[6];
  __shared__ float red[16];
  if (tid < 3) { sc[tid] = logSf[tid]; sc[3 + tid] = wmeta[tid]; }
  __syncthreads();
  const int v = blockIdx.x * 256 + tid;
  const float* born = scr + SCR_BORN;
  float b0 = born[v], b1 = born[VOCAB + v], b2 = born[2 * VOCAB + v];
  o_d[v]             = expf(b0 - sc[0]);
  o_d[VOCAB + v]     = expf(b1 - sc[1]);
  o_d[2 * VOCAB + v] = expf(b2 - sc[2]);
  float s = sc[3] * b0 + sc[4] * b1 + sc[5] * b2;
  float e = expf(s);
  float se  = blockReduceSum(e, red);
  float ses = blockReduceSum(e * s, red);
  if (tid == 0) { wt[blockIdx.x] = se; wt[128 + blockIdx.x] = ses; }
}

// blocks <512: rho_meta rows; blocks >=512: reduce wt -> logS_t, write o_tok
// (block 512 thread 0 also writes H and F = H - S_rho)
__global__ void k_rho_tok(const float* __restrict__ normed, const float* __restrict__ coeff,
                          const float* __restrict__ wmeta, const float* __restrict__ logSf,
                          const float* __restrict__ wt, const float* __restrict__ srho_ws,
                          const float* __restrict__ o_d,
                          float* __restrict__ rho, float* __restrict__ o_tok,
                          float* __restrict__ o_h, float* __restrict__ o_f) {
  const int tid = threadIdx.x;   // 640 blocks x 256
  if (blockIdx.x < 512) {
    const int i = blockIdx.x;
    __shared__ float cr[9];
    if (tid < 9) cr[tid] = coeff[tid] * normed[tid * DD + i];
    __syncthreads();
    for (int j = tid; j < DD; j += 256) {
      float s = 0.f;
#pragma unroll
      for (int k = 0; k < 9; k++) s += cr[k] * normed[k * DD + j];
      rho[i * DD + j] = s;
    }
  } else {
    __shared__ float sc[6];
    __shared__ float red[16];
    if (tid < 3) { sc[tid] = wmeta[tid]; sc[3 + tid] = logSf[tid]; }
    float a_in = (tid < 128) ? wt[tid] : 0.f;
    float b_in = (tid < 128) ? wt[128 + tid] : 0.f;
    float A = blockReduceSum(a_in, red);
    float B = blockReduceSum(b_in, red);
    float lgS = logf(A);
    const int v = (blockIdx.x - 512) * 256 + tid;
    float C = sc[0] * sc[3] + sc[1] * sc[4] + sc[2] * sc[5] - lgS;
    float s = sc[0] * logf(o_d[v]) + sc[1] * logf(o_d[VOCAB + v]) + sc[2] * logf(o_d[2 * VOCAB + v]);
    o_tok[v] = expf(s + C);
    if (blockIdx.x == 512 && tid == 0) {
      float H = lgS - B / A;
      o_h[0] = H;
      o_f[0] = H - srho_ws[0];
    }
  }
}

// ---------------- host launcher ----------------
extern "C" void kernel_launch(void* const* d_in, const int* in_sizes, int n_in,
                              void* d_out, int out_size, void* d_ws, size_t ws_size,
                              hipStream_t stream) {
  const int*   tokens = (const int*)d_in[0];
  const float* E      = (const float*)d_in[1];
  const float* Ws     = (const float*)d_in[2];
  const float* temp_p = (const float*)d_in[3];
  const float* base_p = (const float*)d_in[4];
  const float* sens_p = (const float*)d_in[5];

  float* out   = (float*)d_out;
  float* o_tok = out;                             // [4][32768]
  float* o_rho = o_tok + SEQ * VOCAB;             // [4][512][512]
  float* o_w   = o_rho + (size_t)SEQ * DD * DD;   // [4][3]
  float* o_sr  = o_w + SEQ * NF;                  // [4]
  float* o_h   = o_sr + SEQ;                      // [4]
  float* o_f   = o_h + SEQ;                       // [4]
  float* o_d   = o_f + SEQ;                       // [4][3][32768]

  float* ws       = (float*)d_ws;
  float* w_mem    = ws;            // 4608
  float* w_decay  = ws + 4608;     // 3
  float* w_wbub   = ws + 4624;     // 9
  float* w_normed = ws + 4640;     // 4608 (16B-aligned)
  float* w_wmeta  = ws + 9984;     // 3
  float* w_logSf  = ws + 9988;     // 3
  float* w_coeff  = ws + 9992;     // 9
  float* w_srho   = ws + 10004;    // 1
  float* w_t      = ws + 10240;    // 256

  k_zero<<<18, 256, 0, stream>>>(w_mem, NF * NB * DD);

  for (int t = 0; t < SEQ; t++) {
    float* scr = o_rho + (size_t)t * DD * DD;   // scratch in not-yet-written rho slot
    k_states<<<dim3(9, 8), 256, 0, stream>>>(tokens, E, w_mem, Ws, base_p, sens_p,
                                             w_decay, scr + SCR_ST, t);
    k_equil<<<NF, 256, 0, stream>>>(scr + SCR_ST, w_mem, w_normed, w_wbub, w_decay);
    k_born<<<2048, 256, 0, stream>>>((const float4*)E, (const float4*)w_normed,
                                     w_wbub, scr);
    k_scal<<<1, 256, 0, stream>>>(scr, w_wbub, temp_p, o_w + t * NF, o_sr + t,
                                  w_wmeta, w_logSf, w_coeff, w_srho);
    k_t1<<<128, 256, 0, stream>>>(scr, w_logSf, w_wmeta,
                                  o_d + (size_t)t * NF * VOCAB, w_t);
    k_rho_tok<<<640, 256, 0, stream>>>(w_normed, w_coeff, w_wmeta, w_logSf, w_t, w_srho,
                                       o_d + (size_t)t * NF * VOCAB,
                                       scr, o_tok + (size_t)t * VOCAB, o_h + t, o_f + t);
  }
}

// Round 2
// 325.121 us; speedup vs baseline: 1.3701x; 1.2928x over previous
//
#include <hip/hip_runtime.h>
#include <math.h>

#define VOCAB 32768
#define DD 512
#define NB 3
#define NF 3
#define SEQ 4
#define MAX_ENT_F 10.3972077083991790f

// scratch layout inside o_rho[t] (262144 floats, dead until k_rho_tok):
#define SCR_ST   0        // [9][8][512] states partials = 36864
#define SCR_PART 36864    // [12][2048] born-moment partials = 24576
#define SCR_G    61440    // [45] Gram
#define SCR_BORN 65536    // [3][VOCAB] = 98304

// pair index tables for i<=j over 9 (45 pairs)
__device__ const unsigned char PI9[45] = {
  0,0,0,0,0,0,0,0,0, 1,1,1,1,1,1,1,1, 2,2,2,2,2,2,2, 3,3,3,3,3,3,
  4,4,4,4,4, 5,5,5,5, 6,6,6, 7,7, 8};
__device__ const unsigned char PJ9[45] = {
  0,1,2,3,4,5,6,7,8, 1,2,3,4,5,6,7,8, 2,3,4,5,6,7,8, 3,4,5,6,7,8,
  4,5,6,7,8, 5,6,7,8, 6,7,8, 7,8, 8};

// ---- round-robin Jacobi schedule for n=9 (9 rounds x 4 disjoint pairs; all 36 pairs once) ----
__device__ const unsigned char RP9[9][4] = {
  {1,2,3,4},{0,1,2,3},{0,6,1,2},{0,5,4,1},{0,4,3,2},{0,3,2,1},{0,2,1,7},{0,1,5,6},{0,3,4,5}};
__device__ const unsigned char RQ9[9][4] = {
  {8,7,6,5},{8,6,5,4},{7,8,4,3},{6,7,8,2},{5,6,7,8},{4,5,6,7},{3,4,5,8},{2,3,8,7},{1,8,7,6}};
// per-round, per-index: pair id (4 = bye/identity), sign of s in u_i, partner index
__device__ const unsigned char K9R[9][9] = {
  {4,0,1,2,3,3,2,1,0},
  {0,1,2,3,3,2,1,4,0},
  {0,2,3,3,2,4,1,0,1},
  {0,3,3,4,2,1,0,1,2},
  {0,4,3,2,1,0,1,2,3},
  {0,3,2,1,0,1,2,3,4},
  {0,2,1,0,1,2,4,3,3},
  {0,1,0,1,4,2,3,3,2},
  {0,0,4,1,2,3,3,2,1}};
__device__ const signed char SG9R[9][9] = {
  { 1,-1,-1,-1,-1, 1, 1, 1, 1},
  {-1,-1,-1,-1, 1, 1, 1, 1, 1},
  {-1,-1,-1, 1, 1, 1,-1, 1, 1},
  {-1,-1, 1, 1,-1,-1, 1, 1, 1},
  {-1, 1,-1,-1,-1, 1, 1, 1, 1},
  {-1,-1,-1,-1, 1, 1, 1, 1, 1},
  {-1,-1,-1, 1, 1, 1, 1,-1, 1},
  {-1,-1, 1, 1, 1,-1,-1, 1, 1},
  {-1, 1, 1,-1,-1,-1, 1, 1, 1}};
__device__ const unsigned char PT9R[9][9] = {
  {0,8,7,6,5,4,3,2,1},
  {8,6,5,4,3,2,1,7,0},
  {7,4,3,2,1,5,8,0,6},
  {6,2,1,3,8,7,0,5,4},
  {5,1,8,7,6,0,4,3,2},
  {4,7,6,5,0,3,2,1,8},
  {3,5,4,0,2,1,6,8,7},
  {2,3,0,1,4,8,7,6,5},
  {1,0,2,8,7,6,5,4,3}};

__device__ __forceinline__ float blockReduceSum(float v, float* sh) {
  int lane = threadIdx.x & 63;
  int wid  = threadIdx.x >> 6;
#pragma unroll
  for (int off = 32; off; off >>= 1) v += __shfl_down(v, off, 64);
  __syncthreads();
  if (lane == 0) sh[wid] = v;
  __syncthreads();
  int nw = blockDim.x >> 6;
  float r = 0.0f;
  if ((int)threadIdx.x < nw) r = sh[threadIdx.x];
  if (wid == 0) {
#pragma unroll
    for (int off = 8; off; off >>= 1) r += __shfl_down(r, off, 64);
    if (lane == 0) sh[0] = r;
  }
  __syncthreads();
  return sh[0];
}

__global__ void k_zero(float* p, int n) {
  int i = blockIdx.x * blockDim.x + threadIdx.x;
  if (i < n) p[i] = 0.0f;
}

// pre (redundant per block) + states K-chunk GEMV partials.
// grid (9, 8): fn = f*3+n, dc = K-chunk. 256 threads.
__global__ void k_states(const int* __restrict__ tokens, const float* __restrict__ E,
                         const float* __restrict__ mem, const float* __restrict__ Ws,
                         const float* __restrict__ base_p, const float* __restrict__ sens_p,
                         float* __restrict__ decayArr, float* __restrict__ scr_st, int t) {
  const int fn = blockIdx.x, dc = blockIdx.y, tid = threadIdx.x;
  const int f = fn / NB;
  const int d0 = dc * 64;
  __shared__ float smean[DD];
  __shared__ float xin_loc[64];
  __shared__ float red[16];
  __shared__ float s_decay;
  const float* x = E + (size_t)tokens[t] * DD;
  const float* m = mem + f * (NB * DD);
  for (int d = tid; d < DD; d += 256)
    smean[d] = (m[d] + m[DD + d] + m[2 * DD + d]) * (1.0f / 3.0f);
  __syncthreads();
  float pxm = 0.f, pxx = 0.f, pmm = 0.f;
  for (int d = tid; d < DD; d += 256) {
    float xv = x[d], mv = smean[d];
    pxm += xv * mv; pxx += xv * xv; pmm += mv * mv;
  }
  float sxm = blockReduceSum(pxm, red);
  float sxx = blockReduceSum(pxx, red);
  float smm = blockReduceSum(pmm, red);
  if (tid == 0) {
    float mem_norm = sqrtf(smm) + 1e-10f;
    float x_norm   = sqrtf(sxx) + 1e-10f;
    float novelty  = (mem_norm > 1e-8f) ? (1.0f - sxm / (x_norm * mem_norm)) : 1.0f;
    float sens = fabsf(sens_p[0]);
    float z = base_p[0] - sens * novelty;
    float dec = 1.0f / (1.0f + expf(-z));
    if (dc == 0 && fn % NB == 0) decayArr[f] = dec;
    s_decay = dec;
  }
  __syncthreads();
  if (tid < 64) xin_loc[tid] = x[d0 + tid] + s_decay * smean[d0 + tid];
  __syncthreads();
  const float* W = Ws + (size_t)fn * DD * DD + (size_t)d0 * DD;
  float acc0 = 0.f, acc1 = 0.f;
#pragma unroll 8
  for (int dd = 0; dd < 64; dd++) {
    float xv = xin_loc[dd];
    acc0 += xv * W[dd * DD + tid];
    acc1 += xv * W[dd * DD + tid + 256];
  }
  float* o = scr_st + (fn * 8 + dc) * DD;
  o[tid] = acc0;
  o[tid + 256] = acc1;
}

// sum K-chunks, equilibrate, norms, bubble weights, normed, memory update
__global__ void k_equil(const float* __restrict__ scr_st, float* __restrict__ mem,
                        float* __restrict__ normed, float* __restrict__ wbub,
                        const float* __restrict__ decayArr) {
  const int f = blockIdx.x, tid = threadIdx.x;   // 256 threads
  __shared__ float s[NB * DD];
  __shared__ float red[16];
  __shared__ float snrm[NB];
  for (int i = tid; i < NB * DD; i += 256) {
    int n = i >> 9, e = i & 511;
    const float* src = scr_st + ((f * NB + n) * 8) * DD + e;
    float acc = 0.f;
#pragma unroll
    for (int dc = 0; dc < 8; dc++) acc += src[dc * DD];
    s[i] = acc;
  }
  __syncthreads();
  for (int e = tid; e < DD; e += 256) {
    float a = s[e], b = s[DD + e], c = s[2 * DD + e];
#pragma unroll
    for (int it = 0; it < 3; it++) {
      float mn = (a + b + c) * (1.0f / 3.0f);
      a += 0.3f * (mn - a);
      b += 0.3f * (mn - b);
      c += 0.3f * (mn - c);
    }
    s[e] = a; s[DD + e] = b; s[2 * DD + e] = c;
  }
  __syncthreads();
  for (int n = 0; n < NB; n++) {
    float p = 0.f;
    for (int e = tid; e < DD; e += 256) { float v = s[n * DD + e]; p += v * v; }
    float ss = blockReduceSum(p, red);
    if (tid == 0) snrm[n] = sqrtf(ss);
  }
  __syncthreads();
  if (tid == 0) {
    float n0 = snrm[0], n1 = snrm[1], n2 = snrm[2];
    float mx = fmaxf(2.0f * n0, fmaxf(2.0f * n1, 2.0f * n2));
    float e0 = expf(2.0f * n0 - mx), e1 = expf(2.0f * n1 - mx), e2 = expf(2.0f * n2 - mx);
    float sd = e0 + e1 + e2;
    wbub[f * NB + 0] = e0 / sd;
    wbub[f * NB + 1] = e1 / sd;
    wbub[f * NB + 2] = e2 / sd;
  }
  float dec = decayArr[f];
  for (int i = tid; i < NB * DD; i += 256) {
    int n = i >> 9;
    float sv = s[i];
    normed[f * NB * DD + i] = sv / (snrm[n] + 1e-10f);
    float old = mem[f * NB * DD + i];
    mem[f * NB * DD + i] = dec * old + (1.0f - dec) * sv;
  }
}

// born -> scr_born; 12 moment-partials of u=exp(born) per block; Gram in block 0.
// Reduction restructured: instead of 9 x 6-level shuffle trees per row (108
// reduce ops/row/lane), all 36 partial dots (4 rows x 9 j) per wave go through
// one padded LDS transpose [36][65] (2-way banks both phases = free), then 36
// lanes serially sum 64 values each. Tail (exp/moments) runs on 4 lanes/wave
// concurrently + 2-shfl combine. E row loads double-buffered (prefetch).
__global__ __launch_bounds__(256, 4) void k_born(const float4* __restrict__ E4,
                                                 const float4* __restrict__ N4,
                                                 const float* __restrict__ wbub,
                                                 float* __restrict__ scr) {
  const int tid = threadIdx.x, lane = tid & 63, wave = tid >> 6;
  float* born = scr + SCR_BORN;
  __shared__ float w9[9];
  __shared__ float sb2[12][4];
  __shared__ float tr[4][36 * 65];
  float4 nr0[9], nr1[9];
#pragma unroll
  for (int j = 0; j < 9; j++) {
    nr0[j] = N4[j * 128 + lane];
    nr1[j] = N4[j * 128 + 64 + lane];
  }
  if (tid < 9) w9[tid] = wbub[tid];
  __syncthreads();
  const int vbase = blockIdx.x * 16 + wave * 4;
  float* T = tr[wave];
  // prefetch row 0
  float4 a0 = E4[(size_t)vbase * 128 + lane];
  float4 a1 = E4[(size_t)vbase * 128 + 64 + lane];
#pragma unroll
  for (int r = 0; r < 4; r++) {
    float4 c0 = a0, c1 = a1;
    if (r < 3) {
      a0 = E4[(size_t)(vbase + r + 1) * 128 + lane];
      a1 = E4[(size_t)(vbase + r + 1) * 128 + 64 + lane];
    }
#pragma unroll
    for (int j = 0; j < 9; j++) {
      float4 p = nr0[j], q = nr1[j];
      float acc = c0.x * p.x + c0.y * p.y + c0.z * p.z + c0.w * p.w +
                  c1.x * q.x + c1.y * q.y + c1.z * q.z + c1.w * q.w;
      T[(r * 9 + j) * 65 + lane] = acc;   // banks (r9j+lane)%32: 2-way = free
    }
  }
  // same-wave LDS write->read: program order + lgkmcnt, no barrier needed
  float dot = 0.f;
  if (lane < 36) {
    const float* row = T + lane * 65;     // banks (lane+b)%32: 2-way = free
    float s0 = 0.f, s1 = 0.f, s2 = 0.f, s3 = 0.f;
#pragma unroll
    for (int b = 0; b < 64; b += 4) {
      s0 += row[b]; s1 += row[b + 1]; s2 += row[b + 2]; s3 += row[b + 3];
    }
    dot = (s0 + s1) + (s2 + s3);
  }
  const int rr = lane / 9, jmod = lane - rr * 9;
  float y = 0.f;
  if (lane < 36) y = w9[jmod] * dot * dot;
  float z1 = __shfl_down(y, 1, 64);
  float z2 = __shfl_down(y, 2, 64);
  float bf = y + z1 + z2;                 // valid at jmod in {0,3,6}: b0,b1,b2
  if (lane < 36 && (jmod == 0 || jmod == 3 || jmod == 6)) {
    born[(jmod / 3) * VOCAB + vbase + rr] = bf;
  }
  float b1v = __shfl_down(bf, 3, 64);
  float b2v = __shfl_down(bf, 6, 64);
  float pu0 = 0.f, pu1 = 0.f, pu2 = 0.f;
  float pub0 = 0.f, pub1 = 0.f, pub2 = 0.f;
  float puu0 = 0.f, puu1 = 0.f, puu2 = 0.f;
  float pc01 = 0.f, pc02 = 0.f, pc12 = 0.f;
  if (lane < 36 && jmod == 0) {           // lanes 0,9,18,27 (rows 0..3)
    float b0v = bf;
    float u0 = expf(b0v), u1 = expf(b1v), u2 = expf(b2v);
    pu0 = u0; pu1 = u1; pu2 = u2;
    pub0 = u0 * b0v; pub1 = u1 * b1v; pub2 = u2 * b2v;
    puu0 = u0 * u0; puu1 = u1 * u1; puu2 = u2 * u2;
    pc01 = u0 * u1; pc02 = u0 * u2; pc12 = u1 * u2;
  }
  // combine lanes {0,9,18,27} -> lane 0 (two shfl_down steps: 9 then 18)
#define CMB9(x) do { x += __shfl_down(x, 9, 64); x += __shfl_down(x, 18, 64); } while (0)
  CMB9(pu0);  CMB9(pu1);  CMB9(pu2);
  CMB9(pub0); CMB9(pub1); CMB9(pub2);
  CMB9(puu0); CMB9(puu1); CMB9(puu2);
  CMB9(pc01); CMB9(pc02); CMB9(pc12);
#undef CMB9
  if (lane == 0) {
    sb2[0][wave] = pu0;  sb2[1][wave] = pu1;  sb2[2][wave] = pu2;
    sb2[3][wave] = pub0; sb2[4][wave] = pub1; sb2[5][wave] = pub2;
    sb2[6][wave] = puu0; sb2[7][wave] = puu1; sb2[8][wave] = puu2;
    sb2[9][wave] = pc01; sb2[10][wave] = pc02; sb2[11][wave] = pc12;
  }
  __syncthreads();
  if (tid < 12) {
    float s = sb2[tid][0] + sb2[tid][1] + sb2[tid][2] + sb2[tid][3];
    scr[SCR_PART + tid * 2048 + blockIdx.x] = s;
  }
  // Gram (block 0 only): 45 pairs x 4 lanes
  if (blockIdx.x == 0 && tid < 180) {
    const int p = tid >> 2, sub = tid & 3;
    const float4* ni = N4 + (int)PI9[p] * 128;
    const float4* nj = N4 + (int)PJ9[p] * 128;
    float s = 0.f;
#pragma unroll
    for (int it = 0; it < 32; it++) {
      float4 a = ni[sub * 32 + it];
      float4 b = nj[sub * 32 + it];
      s += a.x * b.x + a.y * b.y + a.z * b.z + a.w * b.w;
    }
    s += __shfl_down(s, 2, 4);
    s += __shfl_down(s, 1, 4);
    if (sub == 0) scr[SCR_G + p] = s;
  }
}

// Reduce 12x2048 partials (4 waves + one barrier), then WAVE 0 ONLY runs the
// scalar head + lane-parallel Jacobi with ZERO further barriers: within one
// wave, LDS write->read ordering is program order + compiler lgkmcnt waits.
// Schedule tables (6 lookups/round) hoisted into registers before the sweep
// loop (r unrolled -> static indexing -> stays in VGPRs, not scratch).
__global__ __launch_bounds__(256, 1) void k_scal(const float* __restrict__ scr,
                                                 const float* __restrict__ wbub,
                                                 const float* __restrict__ temp_p,
                                                 float* __restrict__ o_w, float* __restrict__ o_sr,
                                                 float* __restrict__ wmeta, float* __restrict__ logSf,
                                                 float* __restrict__ coeff, float* __restrict__ srho_ws) {
  const int tid = threadIdx.x, lane = tid & 63, wave = tid >> 6;
  __shared__ float r12[12];
  __shared__ float A2f[162];        // ping-pong 9x9
  __shared__ float csC[5], csS[5];  // slot 4 = identity (bye)
  __shared__ float cf9[9];
  __shared__ float sq9s[9];
#pragma unroll
  for (int jj = 0; jj < 3; jj++) {
    const int j = wave * 3 + jj;
    const float* src = scr + SCR_PART + j * 2048;
    float s = 0.f;
#pragma unroll
    for (int b = 0; b < 32; b++) s += src[lane + b * 64];
#pragma unroll
    for (int off = 32; off; off >>= 1) s += __shfl_down(s, off, 64);
    if (lane == 0) r12[j] = s;
  }
  __syncthreads();
  if (wave != 0) return;
  // ---------------- wave 0 only from here (barrier-free) ----------------
  int li = 0, lj = 0;
  if (lane < 45) { li = PI9[lane]; lj = PJ9[lane]; }
  // hoist per-round schedule into registers (one-time table loads)
  int kiA[9], kjA[9], ipA[9], jpA[9], pA[9], qA[9];
  float sgiA[9], sgjA[9];
#pragma unroll
  for (int r = 0; r < 9; r++) {
    kiA[r] = K9R[r][li];  kjA[r] = K9R[r][lj];
    ipA[r] = PT9R[r][li]; jpA[r] = PT9R[r][lj];
    sgiA[r] = (float)SG9R[r][li]; sgjA[r] = (float)SG9R[r][lj];
    pA[r] = RP9[r][lane & 3]; qA[r] = RQ9[r][lane & 3];
  }
  if (lane == 0) {
    float S0 = r12[0], S1 = r12[1], S2 = r12[2];
    float lg0 = logf(S0), lg1 = logf(S1), lg2 = logf(S2);
    logSf[0] = lg0; logSf[1] = lg1; logSf[2] = lg2;
    float H0 = lg0 - r12[3] / S0;
    float H1 = lg1 - r12[4] / S1;
    float H2 = lg2 - r12[5] / S2;
    float c0 = 1.0f - H0 / MAX_ENT_F;
    float c1 = 1.0f - H1 / MAX_ENT_F;
    float c2 = 1.0f - H2 / MAX_ENT_F;
    float np0 = sqrtf(r12[6]) / S0 + 1e-10f;
    float np1 = sqrtf(r12[7]) / S1 + 1e-10f;
    float np2 = sqrtf(r12[8]) / S2 + 1e-10f;
    float A01 = (r12[9]  / (S0 * S1)) / (np0 * np1);
    float A02 = (r12[10] / (S0 * S2)) / (np0 * np2);
    float A12 = (r12[11] / (S1 * S2)) / (np1 * np2);
    float ag0 = 0.5f * (A01 + A02);
    float ag1 = 0.5f * (A01 + A12);
    float ag2 = 0.5f * (A02 + A12);
    float temp = fmaxf(fabsf(temp_p[0]), 0.01f);
    float z0 = c0 * ag0 / temp, z1 = c1 * ag1 / temp, z2 = c2 * ag2 / temp;
    float mz = fmaxf(z0, fmaxf(z1, z2));
    float e0 = expf(z0 - mz), e1 = expf(z1 - mz), e2 = expf(z2 - mz);
    float sd = e0 + e1 + e2;
    float wm0 = e0 / sd, wm1 = e1 / sd, wm2 = e2 / sd;
    o_w[0] = wm0; o_w[1] = wm1; o_w[2] = wm2;
    wmeta[0] = wm0; wmeta[1] = wm1; wmeta[2] = wm2;
    float cfv[9];
    cfv[0] = wm0 * wbub[0]; cfv[1] = wm0 * wbub[1]; cfv[2] = wm0 * wbub[2];
    cfv[3] = wm1 * wbub[3]; cfv[4] = wm1 * wbub[4]; cfv[5] = wm1 * wbub[5];
    cfv[6] = wm2 * wbub[6]; cfv[7] = wm2 * wbub[7]; cfv[8] = wm2 * wbub[8];
#pragma unroll
    for (int i = 0; i < 9; i++) { coeff[i] = cfv[i]; cf9[i] = cfv[i]; }
    csC[4] = 1.0f; csS[4] = 0.0f;
  }
  if (lane < 9) sq9s[lane] = sqrtf(cf9[lane]);   // same-wave RAW on cf9: ordered
  // init M = diag(sq) G diag(sq), full symmetric 9x9 into buffer 0
  if (lane < 45) {
    float v = sq9s[li] * sq9s[lj] * scr[SCR_G + lane];
    A2f[li * 9 + lj] = v;
    A2f[lj * 9 + li] = v;
  }
#pragma unroll 1
  for (int sweep = 0; sweep < 6; sweep++) {
#pragma unroll
    for (int r = 0; r < 9; r++) {
      const int cur = ((sweep + r) & 1) * 81;
      const int nxt = cur ^ 81;
      if (lane < 4) {
        const int p = pA[r], q = qA[r];
        float app = A2f[cur + p * 10];
        float apq = A2f[cur + p * 9 + q];
        float aqq = A2f[cur + q * 10];
        float den = (fabsf(apq) > 1e-25f) ? apq : 1e-25f;
        float th  = 0.5f * (aqq - app) * __builtin_amdgcn_rcpf(den);
        float mag = __builtin_amdgcn_rcpf(fabsf(th) +
                      __builtin_amdgcn_sqrtf(th * th + 1.f));
        float tt  = copysignf(mag, th);
        float cc  = __builtin_amdgcn_rsqf(tt * tt + 1.f);
        csC[lane] = cc;
        csS[lane] = tt * cc;
      }
      // same-wave: csC/csS write->read ordered by program order + lgkmcnt
      if (lane < 45) {
        float ci = csC[kiA[r]], si = sgiA[r] * csS[kiA[r]];
        float cj = csC[kjA[r]], sj = sgjA[r] * csS[kjA[r]];
        const int ip = ipA[r], jp = jpA[r];
        float v = ci * cj * A2f[cur + li * 9 + lj]
                + ci * sj * A2f[cur + li * 9 + jp]
                + si * cj * A2f[cur + ip * 9 + lj]
                + si * sj * A2f[cur + ip * 9 + jp];
        A2f[nxt + li * 9 + lj] = v;
        A2f[nxt + lj * 9 + li] = v;
      }
    }
  }
  // 54 rounds -> final matrix parity is buffer 0
  if (lane == 0) {
    float total = 503.0f * 1e-12f;
    float ev[9];
#pragma unroll
    for (int i = 0; i < 9; i++) { ev[i] = fmaxf(A2f[i * 10], 1e-12f); total += ev[i]; }
    float S = 0.f;
#pragma unroll
    for (int i = 0; i < 9; i++) {
      float q = ev[i] / total;
      S -= q * fmaxf(logf(q), -100.0f);
    }
    float q0 = 1e-12f / total;
    S -= 503.0f * (q0 * fmaxf(logf(q0), -100.0f));
    o_sr[0] = S; srho_ws[0] = S;
  }
}

// write per-foam probs p=exp(b-logS_f) to o_d; token-softmax partials (shift=0)
__global__ void k_t1(const float* __restrict__ scr, const float* __restrict__ logSf,
                     const float* __restrict__ wmeta, float* __restrict__ o_d,
                     float* __restrict__ wt) {
  const int tid = threadIdx.x;   // 128 blocks x 256
  __shared__ float sc[6];
  __shared__ float red[16];
  if (tid < 3) { sc[tid] = logSf[tid]; sc[3 + tid] = wmeta[tid]; }
  __syncthreads();
  const int v = blockIdx.x * 256 + tid;
  const float* born = scr + SCR_BORN;
  float b0 = born[v], b1 = born[VOCAB + v], b2 = born[2 * VOCAB + v];
  o_d[v]             = expf(b0 - sc[0]);
  o_d[VOCAB + v]     = expf(b1 - sc[1]);
  o_d[2 * VOCAB + v] = expf(b2 - sc[2]);
  float s = sc[3] * b0 + sc[4] * b1 + sc[5] * b2;
  float e = expf(s);
  float se  = blockReduceSum(e, red);
  float ses = blockReduceSum(e * s, red);
  if (tid == 0) { wt[blockIdx.x] = se; wt[128 + blockIdx.x] = ses; }
}

// blocks <512: rho_meta rows; blocks >=512: reduce wt -> logS_t, write o_tok
// (block 512 thread 0 also writes H and F = H - S_rho)
__global__ void k_rho_tok(const float* __restrict__ normed, const float* __restrict__ coeff,
                          const float* __restrict__ wmeta, const float* __restrict__ logSf,
                          const float* __restrict__ wt, const float* __restrict__ srho_ws,
                          const float* __restrict__ o_d,
                          float* __restrict__ rho, float* __restrict__ o_tok,
                          float* __restrict__ o_h, float* __restrict__ o_f) {
  const int tid = threadIdx.x;   // 640 blocks x 256
  if (blockIdx.x < 512) {
    const int i = blockIdx.x;
    __shared__ float cr[9];
    if (tid < 9) cr[tid] = coeff[tid] * normed[tid * DD + i];
    __syncthreads();
    for (int j = tid; j < DD; j += 256) {
      float s = 0.f;
#pragma unroll
      for (int k = 0; k < 9; k++) s += cr[k] * normed[k * DD + j];
      rho[i * DD + j] = s;
    }
  } else {
    __shared__ float sc[6];
    __shared__ float red[16];
    if (tid < 3) { sc[tid] = wmeta[tid]; sc[3 + tid] = logSf[tid]; }
    float a_in = (tid < 128) ? wt[tid] : 0.f;
    float b_in = (tid < 128) ? wt[128 + tid] : 0.f;
    float A = blockReduceSum(a_in, red);
    float B = blockReduceSum(b_in, red);
    float lgS = logf(A);
    const int v = (blockIdx.x - 512) * 256 + tid;
    float C = sc[0] * sc[3] + sc[1] * sc[4] + sc[2] * sc[5] - lgS;
    float s = sc[0] * logf(o_d[v]) + sc[1] * logf(o_d[VOCAB + v]) + sc[2] * logf(o_d[2 * VOCAB + v]);
    o_tok[v] = expf(s + C);
    if (blockIdx.x == 512 && tid == 0) {
      float H = lgS - B / A;
      o_h[0] = H;
      o_f[0] = H - srho_ws[0];
    }
  }
}

// ---------------- host launcher ----------------
extern "C" void kernel_launch(void* const* d_in, const int* in_sizes, int n_in,
                              void* d_out, int out_size, void* d_ws, size_t ws_size,
                              hipStream_t stream) {
  const int*   tokens = (const int*)d_in[0];
  const float* E      = (const float*)d_in[1];
  const float* Ws     = (const float*)d_in[2];
  const float* temp_p = (const float*)d_in[3];
  const float* base_p = (const float*)d_in[4];
  const float* sens_p = (const float*)d_in[5];

  float* out   = (float*)d_out;
  float* o_tok = out;                             // [4][32768]
  float* o_rho = o_tok + SEQ * VOCAB;             // [4][512][512]
  float* o_w   = o_rho + (size_t)SEQ * DD * DD;   // [4][3]
  float* o_sr  = o_w + SEQ * NF;                  // [4]
  float* o_h   = o_sr + SEQ;                      // [4]
  float* o_f   = o_h + SEQ;                       // [4]
  float* o_d   = o_f + SEQ;                       // [4][3][32768]

  float* ws       = (float*)d_ws;
  float* w_mem    = ws;            // 4608
  float* w_decay  = ws + 4608;     // 3
  float* w_wbub   = ws + 4624;     // 9
  float* w_normed = ws + 4640;     // 4608 (16B-aligned)
  float* w_wmeta  = ws + 9984;     // 3
  float* w_logSf  = ws + 9988;     // 3
  float* w_coeff  = ws + 9992;     // 9
  float* w_srho   = ws + 10004;    // 1
  float* w_t      = ws + 10240;    // 256

  k_zero<<<18, 256, 0, stream>>>(w_mem, NF * NB * DD);

  for (int t = 0; t < SEQ; t++) {
    float* scr = o_rho + (size_t)t * DD * DD;   // scratch in not-yet-written rho slot
    k_states<<<dim3(9, 8), 256, 0, stream>>>(tokens, E, w_mem, Ws, base_p, sens_p,
                                             w_decay, scr + SCR_ST, t);
    k_equil<<<NF, 256, 0, stream>>>(scr + SCR_ST, w_mem, w_normed, w_wbub, w_decay);
    k_born<<<2048, 256, 0, stream>>>((const float4*)E, (const float4*)w_normed,
                                     w_wbub, scr);
    k_scal<<<1, 256, 0, stream>>>(scr, w_wbub, temp_p, o_w + t * NF, o_sr + t,
                                  w_wmeta, w_logSf, w_coeff, w_srho);
    k_t1<<<128, 256, 0, stream>>>(scr, w_logSf, w_wmeta,
                                  o_d + (size_t)t * NF * VOCAB, w_t);
    k_rho_tok<<<640, 256, 0, stream>>>(w_normed, w_coeff, w_wmeta, w_logSf, w_t, w_srho,
                                       o_d + (size_t)t * NF * VOCAB,
                                       scr, o_tok + (size_t)t * VOCAB, o_h + t, o_f + t);
  }
}